// Round 13
// baseline (293.403 us; speedup 1.0000x reference)
//
#include <hip/hip_runtime.h>
#include <hip/hip_bf16.h>
#include <stdint.h>

// CapsNet forward. B=512, conv1 1->256 9x9 s1 (28->20), pc 256->256 9x9 s2 (20->6),
// routes R=1152, caps C=10, I=8, O=16, encoder 160->512->9.
// R13: pcgemm BN 128->64 (grid 1152 = 4.5 blk/CU, latency fix via occupancy);
// rgemm ksplit 72; c1gemm grid 1600; enc 4-batch; w2t merged into prep.

typedef __bf16 bf16_t;
typedef __bf16 bf16x4 __attribute__((ext_vector_type(4)));
typedef __bf16 bf16x8 __attribute__((ext_vector_type(8)));
typedef float f32x4 __attribute__((ext_vector_type(4)));
typedef int i32x4 __attribute__((ext_vector_type(4)));
typedef int i32x8 __attribute__((ext_vector_type(8)));

__device__ __forceinline__ void gload_lds16(const void* g, void* l) {
    __builtin_amdgcn_global_load_lds((const __attribute__((address_space(1))) void*)g,
                                     (__attribute__((address_space(3))) void*)l, 16, 0, 0);
}

#define MEMBAR() asm volatile("" ::: "memory")

// f32 -> e4m3 byte (RNE via v_cvt_pk_fp8_f32)
__device__ __forceinline__ uint8_t fp8b(float v) {
    return (uint8_t)(__builtin_amdgcn_cvt_pk_fp8_f32(v, 0.f, 0, false) & 0xFF);
}

// ---------------- merged prep: bij=0, w1t, Bc1, w2t8 ----------------
// blocks: [0,45) bij ; [45,365) w1t ; [365,469) Bc1 ; [469,725) w2t8 (oc = blk-469)
__global__ __launch_bounds__(256) void k_prep(const float* __restrict__ w1,
                                              const float* __restrict__ cw,
                                              const float* __restrict__ pcw,
                                              float* __restrict__ w1t,
                                              bf16_t* __restrict__ Bc1,
                                              float* __restrict__ bij,
                                              uint8_t* __restrict__ w2t8) {
    __shared__ uint16_t tmp16[10368];
    int blk = blockIdx.x, tid = threadIdx.x;
    if (blk < 45) {
        int i = blk * 256 + tid;
        if (i < 11520) bij[i] = 0.f;
    } else if (blk < 365) {
        int i = (blk - 45) * 256 + tid;  // 81920
        int j = i / 160, k = i % 160;
        w1t[k * 512 + j] = w1[i];
    } else if (blk < 469) {
        int i = (blk - 365) * 256 + tid;  // 26624
        if (i < 26624) {
            int oc = i / 104, k = i % 104;
            Bc1[i] = (k < 81) ? (bf16_t)cw[oc * 81 + k] : (bf16_t)0.f;
        }
    } else {
        // pc_w f32 [oc][ic][81] -> w2t8 fp8 [oc][k], k = t*256+ic, value = fp8(pc_w*64)
        int oc = blk - 469;
        const float* src = pcw + (size_t)oc * 20736;
        for (int q2 = tid; q2 < 10368; q2 += 256) {
            float a = src[q2 * 2] * 64.f;
            float b = src[q2 * 2 + 1] * 64.f;
            uint32_t pk = __builtin_amdgcn_cvt_pk_fp8_f32(a, b, 0, false);
            tmp16[q2] = (uint16_t)(pk & 0xFFFF);
        }
        __syncthreads();
        uint32_t* dst = (uint32_t*)(w2t8 + (size_t)oc * 20736);
        for (int w = tid; w < 5184; w += 256) {
            int k = w * 4;
            int t = k >> 8, ic0 = k & 255;
            uint32_t r = 0;
#pragma unroll
            for (int j = 0; j < 4; ++j) {
                int s = (ic0 + j) * 81 + t;
                uint32_t b = (tmp16[s >> 1] >> ((s & 1) * 8)) & 0xFF;
                r |= b << (8 * j);
            }
            dst[w] = r;
        }
    }
}

// ---------------- conv1 as MFMA GEMM, vectorized in-LDS im2col -> xt8 fp8 [m][256] ----------------
// M=204800 (1600 tiles of 128), N=256, K=96 (3 kk). grid 1600, 1 tile each; 8 waves (2m x 4n).
// LDS = As 26,624 + Bs 53,248 = 79,872 B <= 80 KiB -> 2 blocks/CU.
__global__ __launch_bounds__(512) void k_c1gemm(const float* __restrict__ data,
                                                const bf16_t* __restrict__ Bc1,
                                                const float* __restrict__ cb,
                                                uint8_t* __restrict__ xt8) {
    __shared__ __align__(16) bf16_t As[128 * 104];  // 26,624 B
    __shared__ __align__(16) bf16_t Bs[256 * 104];  // 53,248 B
    int tid = threadIdx.x, lane = tid & 63, wave = tid >> 6;
    int wm = wave >> 2, wn = wave & 3;
    for (int i = tid; i < 3328; i += 512) {
        int byte = i * 16;
        int r = byte / 208;
        int c16 = (byte - r * 208) >> 4;
        gload_lds16(Bc1 + r * 104 + c16 * 8, (char*)Bs + byte);
    }
    int mr = wm * 64 + (lane & 15);
    int nr = wn * 64 + (lane & 15);
    float bias[4];
#pragma unroll
    for (int nj = 0; nj < 4; ++nj) bias[nj] = cb[nr + nj * 16];

    int m0 = blockIdx.x * 128;
    // zero the pad columns 81..103
    for (int z = tid; z < 128 * 23; z += 512) {
        int r = z / 23, k = 81 + z - (z / 23) * 23;
        As[r * 104 + k] = (bf16_t)0.f;
    }
    // fill: (row, kh) pairs, 9 contiguous floats each
    for (int pr = tid; pr < 1152; pr += 512) {
        int r = pr / 9, kh = pr - (pr / 9) * 9;
        int m = m0 + r;
        int b = m / 400, pos = m - b * 400;
        int oh = pos / 20, ow = pos - oh * 20;
        const float* src = data + (size_t)b * 784 + (oh + kh) * 28 + ow;
        bf16_t* dst = &As[r * 104 + kh * 9];
#pragma unroll
        for (int j = 0; j < 9; ++j) dst[j] = (bf16_t)src[j];
    }
    asm volatile("s_waitcnt vmcnt(0)" ::: "memory");  // Bs gload drained
    __syncthreads();  // As + Bs ready
    f32x4 acc[4][4];
#pragma unroll
    for (int mi = 0; mi < 4; ++mi)
#pragma unroll
        for (int nj = 0; nj < 4; ++nj) acc[mi][nj] = (f32x4){0.f, 0.f, 0.f, 0.f};
#pragma unroll
    for (int kk = 0; kk < 3; ++kk) {
        int ch = (kk * 4 + (lane >> 4)) * 8;
        bf16x8 af[4], bfr[4];
#pragma unroll
        for (int i = 0; i < 4; ++i) af[i] = *(const bf16x8*)&As[(mr + i * 16) * 104 + ch];
#pragma unroll
        for (int j = 0; j < 4; ++j) bfr[j] = *(const bf16x8*)&Bs[(nr + j * 16) * 104 + ch];
#pragma unroll
        for (int mi = 0; mi < 4; ++mi)
#pragma unroll
            for (int nj = 0; nj < 4; ++nj)
                acc[mi][nj] = __builtin_amdgcn_mfma_f32_16x16x32_bf16(af[mi], bfr[nj], acc[mi][nj], 0, 0, 0);
    }
    int mbase = m0 + wm * 64 + (lane >> 4) * 4;
#pragma unroll
    for (int mi = 0; mi < 4; ++mi)
#pragma unroll
        for (int nj = 0; nj < 4; ++nj)
#pragma unroll
            for (int j = 0; j < 4; ++j)
                xt8[(size_t)(mbase + mi * 16 + j) * 256 + nr + nj * 16] =
                    fp8b(fmaxf(acc[mi][nj][j] + bias[nj], 0.f));
}

// ---------------- PrimaryCaps implicit GEMM, MX-fp8, BN=64 occupancy build ----------------
// grid 1152 = 144 m-tiles x 4 n-tiles(64) x 2 k-splits ; tile 128x64, BK=128 B, 81 steps.
// LDS 24 KB, acc 32 VGPR -> ~4.5+ blocks/CU co-resident (latency hidden by TLP).
// Scales: A = 2^0 (0x7F), B = 2^-6 (0x79, undoes the x64 in w2t8).
__global__ __launch_bounds__(256) void k_pcgemm(const uint8_t* __restrict__ xt8,
                                                const uint8_t* __restrict__ w2t8,
                                                bf16_t* __restrict__ parts) {
    __shared__ __align__(16) uint8_t As[128 * 128];  // 16 KB
    __shared__ __align__(16) uint8_t Bs[64 * 128];   //  8 KB
    int bid = blockIdx.x;
    int mt = bid % 144;
    int nt = (bid / 144) & 3;
    int ks = bid / 576;  // 0..1
    int m0 = mt * 128, n0 = nt * 64;
    int tid = threadIdx.x, lane = tid & 63, wave = tid >> 6;

    int csrc = (tid & 7) ^ ((tid >> 3) & 7);  // swizzled source chunk (16-B units)
    int arow[4];
#pragma unroll
    for (int p = 0; p < 4; ++p) {
        int m = m0 + p * 32 + (tid >> 3);
        int bb = m / 36, pos = m % 36;
        int oh = pos / 6, ow = pos % 6;
        arow[p] = ((bb * 20 + oh * 2) * 20 + ow * 2) * 256;
    }
    const uint8_t* bbase = w2t8 + (size_t)(n0 + (tid >> 3)) * 20736 + csrc * 16;

    f32x4 acc[4][2];
#pragma unroll
    for (int mi = 0; mi < 4; ++mi)
#pragma unroll
        for (int ni = 0; ni < 2; ++ni) acc[mi][ni] = (f32x4){0.f, 0.f, 0.f, 0.f};

    int g0 = ks * 81;
    int mr = (wave >> 1) * 64 + (lane & 15);
    int nr = (wave & 1) * 32 + (lane & 15);
    int rx = lane & 7;
    int c0 = (2 * (lane >> 4)) ^ rx;
    int c1 = (2 * (lane >> 4) + 1) ^ rx;

    for (int it = 0; it < 81; ++it) {
        int g = g0 + it;
        int t = g >> 1, icb = g & 1;
        int kh = t / 9, kw = t - (t / 9) * 9;
        int aoff = (kh * 20 + kw) * 256 + icb * 128 + csrc * 16;
#pragma unroll
        for (int p = 0; p < 4; ++p)
            gload_lds16(xt8 + arow[p] + aoff, &As[p * 4096 + tid * 16]);
#pragma unroll
        for (int p = 0; p < 2; ++p)
            gload_lds16(bbase + (size_t)p * 32 * 20736 + (size_t)g * 128, &Bs[p * 4096 + tid * 16]);
        __syncthreads();
        i32x8 af[4], bfr[2];
#pragma unroll
        for (int i = 0; i < 4; ++i) {
            i32x4 lo = *(const i32x4*)&As[(mr + i * 16) * 128 + c0 * 16];
            i32x4 hi = *(const i32x4*)&As[(mr + i * 16) * 128 + c1 * 16];
            af[i][0] = lo[0]; af[i][1] = lo[1]; af[i][2] = lo[2]; af[i][3] = lo[3];
            af[i][4] = hi[0]; af[i][5] = hi[1]; af[i][6] = hi[2]; af[i][7] = hi[3];
        }
#pragma unroll
        for (int i = 0; i < 2; ++i) {
            i32x4 lo = *(const i32x4*)&Bs[(nr + i * 16) * 128 + c0 * 16];
            i32x4 hi = *(const i32x4*)&Bs[(nr + i * 16) * 128 + c1 * 16];
            bfr[i][0] = lo[0]; bfr[i][1] = lo[1]; bfr[i][2] = lo[2]; bfr[i][3] = lo[3];
            bfr[i][4] = hi[0]; bfr[i][5] = hi[1]; bfr[i][6] = hi[2]; bfr[i][7] = hi[3];
        }
#pragma unroll
        for (int mi = 0; mi < 4; ++mi)
#pragma unroll
            for (int ni = 0; ni < 2; ++ni)
                acc[mi][ni] = __builtin_amdgcn_mfma_scale_f32_16x16x128_f8f6f4(
                    af[mi], bfr[ni], acc[mi][ni], 0, 0, 0, 0x7F7F7F7F, 0, 0x79797979);
        __syncthreads();
    }

    bf16_t* out = parts + (size_t)ks * 4718592;
    int mbase = m0 + (wave >> 1) * 64 + (lane >> 4) * 4;
    int nbase = n0 + (wave & 1) * 32 + (lane & 15);
#pragma unroll
    for (int mi = 0; mi < 4; ++mi)
#pragma unroll
        for (int ni = 0; ni < 2; ++ni)
#pragma unroll
            for (int j = 0; j < 4; ++j)
                out[(size_t)(mbase + mi * 16 + j) * 256 + nbase + ni * 16] = (bf16_t)acc[mi][ni][j];
}

// ---------------- squash -> u bf16 [b][flat], flat = oc*36+pos ----------------
__global__ __launch_bounds__(256) void k_squash(const bf16_t* __restrict__ parts,
                                                const float* __restrict__ pcb,
                                                bf16_t* __restrict__ ub) {
    __shared__ float s[36 * 257];
    int b = blockIdx.x, tid = threadIdx.x;
    for (int i = tid; i < 9216; i += 256) {
        float a = pcb[i & 255];
#pragma unroll
        for (int p = 0; p < 2; ++p) a += (float)parts[(size_t)p * 4718592 + (size_t)b * 9216 + i];
        s[(i >> 8) * 257 + (i & 255)] = a;
    }
    __syncthreads();
    for (int r = tid; r < 1152; r += 256) {
        int flat0 = r * 8;
        float val[8], sn = 0.f;
#pragma unroll
        for (int e = 0; e < 8; ++e) {
            int f = flat0 + e;
            float x = s[(f % 36) * 257 + f / 36];
            val[e] = x;
            sn += x * x;
        }
        float scale = sn / ((1.f + sn) * sqrtf(sn));
        bf16x8 vv;
#pragma unroll
        for (int e = 0; e < 8; ++e) vv[e] = (bf16_t)(val[e] * scale);
        *(bf16x8*)&ub[(size_t)b * 9216 + flat0] = vv;
    }
}

// ---------------- u bf16 [512][9216] -> uT bf16 [9216][512] ----------------
__global__ __launch_bounds__(256) void k_uT(const bf16_t* __restrict__ ub, bf16_t* __restrict__ uT) {
    __shared__ bf16_t t[64 * 66];
    int kt = blockIdx.x % 144, bt = blockIdx.x / 144;
    int k0 = kt * 64, b0 = bt * 64;
    int tid = threadIdx.x;
    int c8 = tid & 7;
#pragma unroll
    for (int p = 0; p < 2; ++p) {
        int r = p * 32 + (tid >> 3);  // b-local
        bf16x8 vv = *(const bf16x8*)&ub[(size_t)(b0 + r) * 9216 + k0 + c8 * 8];
        uint32_t u4[4];
        *(bf16x8*)u4 = vv;
#pragma unroll
        for (int j2 = 0; j2 < 4; ++j2)
            *(uint32_t*)&t[r * 66 + c8 * 8 + j2 * 2] = u4[j2];
    }
    __syncthreads();
#pragma unroll
    for (int p = 0; p < 2; ++p) {
        int kp = p * 32 + (tid >> 3);  // k-local
        bf16x8 vv;
#pragma unroll
        for (int j = 0; j < 8; ++j) vv[j] = t[(c8 * 8 + j) * 66 + kp];
        *(bf16x8*)&uT[(size_t)(k0 + kp) * 512 + b0 + c8 * 8] = vv;
    }
}

// ---------------- cij = softmax_r(bij) per caps column (10 blocks) ----------------
__global__ void k_cij(const float* __restrict__ bij, float* __restrict__ cij) {
    __shared__ float red[256];
    int c = blockIdx.x, tid = threadIdx.x;
    float mx = -1e30f;
    for (int r = tid; r < 1152; r += 256) mx = fmaxf(mx, bij[r * 10 + c]);
    red[tid] = mx; __syncthreads();
    for (int s = 128; s > 0; s >>= 1) { if (tid < s) red[tid] = fmaxf(red[tid], red[tid + s]); __syncthreads(); }
    float MX = red[0]; __syncthreads();
    float sm = 0.f;
    for (int r = tid; r < 1152; r += 256) sm += expf(bij[r * 10 + c] - MX);
    red[tid] = sm; __syncthreads();
    for (int s = 128; s > 0; s >>= 1) { if (tid < s) red[tid] += red[tid + s]; __syncthreads(); }
    float inv = 1.f / red[0];
    for (int r = tid; r < 1152; r += 256) cij[r * 10 + c] = expf(bij[r * 10 + c] - MX) * inv;
}

// ---------------- fold: cw2T[co][k] = cij[r][c] * W[r][c][o][i] ----------------
__global__ void k_fold(const float* __restrict__ cij, const float* __restrict__ W,
                       bf16_t* __restrict__ cw2T) {
    int idx = blockIdx.x * 256 + threadIdx.x;  // 1474560, co-major
    int co = idx / 9216, k = idx % 9216;
    int r = k >> 3, i = k & 7;
    int c = co >> 4, o = co & 15;
    cw2T[idx] = (bf16_t)(cij[r * 10 + c] * W[((size_t)(r * 10 + c) * 16 + o) * 8 + i]);
}

// fold for iter0: bij=0 -> cij = 1/1152 uniform
__global__ void k_fold0(const float* __restrict__ W, bf16_t* __restrict__ cw2T) {
    int idx = blockIdx.x * 256 + threadIdx.x;  // 1474560
    int co = idx / 9216, k = idx % 9216;
    int r = k >> 3, i = k & 7;
    int c = co >> 4, o = co & 15;
    cw2T[idx] = (bf16_t)(W[((size_t)(r * 10 + c) * 16 + o) * 8 + i] * (1.0f / 1152.0f));
}

// ---------------- NT MFMA kernel: sp[ks][M][160] (bf16) = A[M][K] x B[160][K]^T ----------------
__global__ __launch_bounds__(256) void k_rgemm(const bf16_t* __restrict__ A,
                                               const bf16_t* __restrict__ B,
                                               bf16_t* __restrict__ Cp,
                                               int Kfull, int steps, int mtiles) {
    __shared__ __align__(16) bf16_t As[64 * 64];
    __shared__ __align__(16) bf16_t Bs[160 * 64];
    int bid = blockIdx.x;
    int mt = bid % mtiles, ks = bid / mtiles;
    int m0 = mt * 64;
    int k0 = ks * steps * 64;
    int tid = threadIdx.x, lane = tid & 63, wave = tid >> 6;
    int srow = tid >> 3;                       // 0..31
    int csrc = (tid & 7) ^ (srow & 7);
    const bf16_t* asrc[2];
    const bf16_t* bsrc[5];
#pragma unroll
    for (int p = 0; p < 2; ++p)
        asrc[p] = A + (size_t)(m0 + p * 32 + srow) * Kfull + k0 + csrc * 8;
#pragma unroll
    for (int p = 0; p < 5; ++p)
        bsrc[p] = B + (size_t)(p * 32 + srow) * Kfull + k0 + csrc * 8;

    f32x4 acc[2][5];
#pragma unroll
    for (int mi = 0; mi < 2; ++mi)
#pragma unroll
        for (int nj = 0; nj < 5; ++nj) acc[mi][nj] = (f32x4){0.f, 0.f, 0.f, 0.f};

    int mr = (wave >> 1) * 32 + (lane & 15);
    int nr = (wave & 1) * 80 + (lane & 15);
    int rx = lane & 7;

    for (int it = 0; it < steps; ++it) {
#pragma unroll
        for (int p = 0; p < 2; ++p) gload_lds16(asrc[p] + it * 64, As + p * 2048 + tid * 8);
#pragma unroll
        for (int p = 0; p < 5; ++p) gload_lds16(bsrc[p] + it * 64, Bs + p * 2048 + tid * 8);
        __syncthreads();
#pragma unroll
        for (int kk = 0; kk < 2; ++kk) {
            int ch = ((kk * 4 + (lane >> 4)) ^ rx) * 8;
            bf16x8 af[2], bfr[5];
#pragma unroll
            for (int i = 0; i < 2; ++i) af[i] = *(const bf16x8*)&As[(mr + i * 16) * 64 + ch];
#pragma unroll
            for (int j = 0; j < 5; ++j) bfr[j] = *(const bf16x8*)&Bs[(nr + j * 16) * 64 + ch];
#pragma unroll
            for (int mi = 0; mi < 2; ++mi)
#pragma unroll
                for (int nj = 0; nj < 5; ++nj)
                    acc[mi][nj] = __builtin_amdgcn_mfma_f32_16x16x32_bf16(af[mi], bfr[nj], acc[mi][nj], 0, 0, 0);
        }
        __syncthreads();
    }

    bf16_t* out = Cp + (size_t)ks * ((size_t)mtiles * 64 * 160);
    int mbase = m0 + (wave >> 1) * 32 + (lane >> 4) * 4;
    int nbase = (wave & 1) * 80 + (lane & 15);
#pragma unroll
    for (int mi = 0; mi < 2; ++mi)
#pragma unroll
        for (int nj = 0; nj < 5; ++nj)
#pragma unroll
            for (int j = 0; j < 4; ++j)
                out[(size_t)(mbase + mi * 16 + j) * 160 + nbase + nj * 16] = (bf16_t)acc[mi][nj][j];
}

// ---------------- v + vT from bf16 s partials (72 splits) ----------------
__global__ void k_vcomp(const bf16_t* __restrict__ sp, float* __restrict__ v,
                        bf16_t* __restrict__ vT) {
    int idx = blockIdx.x * 256 + threadIdx.x;  // 81920
    float s = 0.f;
    for (int p = 0; p < 72; ++p) s += (float)sp[(size_t)p * 81920 + idx];
    float val = s * fabsf(s) / (1.f + s * s);
    v[idx] = val;
    int b = idx / 160, co = idx % 160;
    vT[(size_t)co * 512 + b] = (bf16_t)val;
}

// ---------------- G-gemm + amean fused ----------------
__global__ __launch_bounds__(256) void k_ggemm2(const bf16_t* __restrict__ uT,
                                                const bf16_t* __restrict__ vT,
                                                const float* __restrict__ W,
                                                float* __restrict__ bij) {
    __shared__ __align__(16) bf16_t As[64 * 64];
    __shared__ __align__(16) bf16_t Bs[160 * 64];
    __shared__ float Gl[64 * 161];
    int mt = blockIdx.x;
    int m0 = mt * 64;
    int tid = threadIdx.x, lane = tid & 63, wave = tid >> 6;
    int srow = tid >> 3;
    int csrc = (tid & 7) ^ (srow & 7);
    const bf16_t* asrc[2];
    const bf16_t* bsrc[5];
#pragma unroll
    for (int p = 0; p < 2; ++p)
        asrc[p] = uT + (size_t)(m0 + p * 32 + srow) * 512 + csrc * 8;
#pragma unroll
    for (int p = 0; p < 5; ++p)
        bsrc[p] = vT + (size_t)(p * 32 + srow) * 512 + csrc * 8;

    f32x4 acc[2][5];
#pragma unroll
    for (int mi = 0; mi < 2; ++mi)
#pragma unroll
        for (int nj = 0; nj < 5; ++nj) acc[mi][nj] = (f32x4){0.f, 0.f, 0.f, 0.f};

    int mr = (wave >> 1) * 32 + (lane & 15);
    int nr = (wave & 1) * 80 + (lane & 15);
    int rx = lane & 7;

    for (int it = 0; it < 8; ++it) {
#pragma unroll
        for (int p = 0; p < 2; ++p) gload_lds16(asrc[p] + it * 64, As + p * 2048 + tid * 8);
#pragma unroll
        for (int p = 0; p < 5; ++p) gload_lds16(bsrc[p] + it * 64, Bs + p * 2048 + tid * 8);
        __syncthreads();
#pragma unroll
        for (int kk = 0; kk < 2; ++kk) {
            int ch = ((kk * 4 + (lane >> 4)) ^ rx) * 8;
            bf16x8 af[2], bfr[5];
#pragma unroll
            for (int i = 0; i < 2; ++i) af[i] = *(const bf16x8*)&As[(mr + i * 16) * 64 + ch];
#pragma unroll
            for (int j = 0; j < 5; ++j) bfr[j] = *(const bf16x8*)&Bs[(nr + j * 16) * 64 + ch];
#pragma unroll
            for (int mi = 0; mi < 2; ++mi)
#pragma unroll
                for (int nj = 0; nj < 5; ++nj)
                    acc[mi][nj] = __builtin_amdgcn_mfma_f32_16x16x32_bf16(af[mi], bfr[nj], acc[mi][nj], 0, 0, 0);
        }
        __syncthreads();
    }

    int mbl = (wave >> 1) * 32 + (lane >> 4) * 4;
    int nbase = (wave & 1) * 80 + (lane & 15);
#pragma unroll
    for (int mi = 0; mi < 2; ++mi)
#pragma unroll
        for (int nj = 0; nj < 5; ++nj)
#pragma unroll
            for (int j = 0; j < 4; ++j)
                Gl[(mbl + mi * 16 + j) * 161 + nbase + nj * 16] = acc[mi][nj][j] * (1.0f / 512.0f);
    __syncthreads();
    if (tid < 80) {
        int rl = tid / 10, c = tid % 10;
        int r = mt * 8 + rl;
        const float* wbase = W + (size_t)(r * 10 + c) * 128;
        float s = 0.f;
#pragma unroll
        for (int o = 0; o < 16; ++o)
#pragma unroll
            for (int i = 0; i < 8; ++i)
                s += wbase[o * 8 + i] * Gl[(rl * 8 + i) * 161 + c * 16 + o];
        bij[r * 10 + c] += s;
    }
}

// ---------------- encoder, 4 images per block (grid 128) ----------------
__global__ __launch_bounds__(256) void k_enc(const float* __restrict__ v,
                                             const float* __restrict__ w1t,
                                             const float* __restrict__ b1,
                                             const float* __restrict__ w2,
                                             const float* __restrict__ b2,
                                             float* __restrict__ out) {
    __shared__ float fl[4 * 160];
    __shared__ float h[4 * 512];
    int b0 = blockIdx.x * 4, tid = threadIdx.x;
    for (int i = tid; i < 640; i += 256) fl[i] = v[(size_t)b0 * 160 + i];
    __syncthreads();
    for (int j = tid; j < 512; j += 256) {
        float bb = b1[j];
        float a0 = bb, a1 = bb, a2 = bb, a3 = bb;
        for (int k = 0; k < 160; ++k) {
            float w = w1t[k * 512 + j];
            a0 += fl[k] * w;
            a1 += fl[160 + k] * w;
            a2 += fl[320 + k] * w;
            a3 += fl[480 + k] * w;
        }
        h[j] = fmaxf(a0, 0.f);
        h[512 + j] = fmaxf(a1, 0.f);
        h[1024 + j] = fmaxf(a2, 0.f);
        h[1536 + j] = fmaxf(a3, 0.f);
    }
    __syncthreads();
    int wave = tid >> 6, lane = tid & 63;
    int q = wave;  // image 0..3
    for (int j = 0; j < 9; ++j) {
        float p = 0.f;
#pragma unroll
        for (int l = lane; l < 512; l += 64) p += h[q * 512 + l] * w2[j * 512 + l];
#pragma unroll
        for (int off = 32; off > 0; off >>= 1) p += __shfl_down(p, off, 64);
        if (lane == 0) out[(b0 + q) * 9 + j] = 1.f / (1.f + expf(-(p + b2[j])));
    }
}

// ---------------- launch ----------------
extern "C" void kernel_launch(void* const* d_in, const int* in_sizes, int n_in,
                              void* d_out, int out_size, void* d_ws, size_t ws_size,
                              hipStream_t stream) {
    const float* data   = (const float*)d_in[0];
    const float* conv_w = (const float*)d_in[1];
    const float* conv_b = (const float*)d_in[2];
    const float* pc_w   = (const float*)d_in[3];
    const float* pc_b   = (const float*)d_in[4];
    const float* W      = (const float*)d_in[5];
    const float* enc_w1 = (const float*)d_in[6];
    const float* enc_b1 = (const float*)d_in[7];
    const float* enc_w2 = (const float*)d_in[8];
    const float* enc_b2 = (const float*)d_in[9];

    char* ws = (char*)d_ws;
    uint8_t* xt8   = (uint8_t*)(ws + 0);           //  52,428,800
    uint8_t* w2t8  = (uint8_t*)(ws + 52428800);    //   5,308,416 ->  57,737,216
    bf16_t*  parts = (bf16_t*)(ws + 57737216);     //  18,874,368 (2 x 9,437,184 B) -> 76,611,584
    bf16_t*  uT    = (bf16_t*)(ws + 76611584);     //   9,437,184 ->  86,048,768
    bf16_t*  cw2T  = (bf16_t*)(ws + 86048768);     //   2,949,120 ->  88,997,888
    bf16_t*  sp    = (bf16_t*)(ws + 88997888);     //  11,796,480 (72 x 163,840 B) -> 100,794,368
    bf16_t*  ub    = (bf16_t*)(ws + 100794368);    //   9,437,184 -> 110,231,552
    float*   v     = (float*)(ws + 110231552);     //     327,680 -> 110,559,232
    bf16_t*  vT    = (bf16_t*)(ws + 110559232);    //     163,840 -> 110,723,072
    float*   w1t   = (float*)(ws + 110723072);     //     327,680 -> 111,050,752
    float*   bij   = (float*)(ws + 111050752);     //      46,080 -> 111,096,832
    float*   cij   = (float*)(ws + 111096832);     //      46,080 -> 111,142,912
    bf16_t*  Bc1   = (bf16_t*)(ws + 111142912);    //      53,248 -> 111,196,160 total
    float*   outp  = (float*)d_out;

    hipLaunchKernelGGL(k_prep, dim3(725), dim3(256), 0, stream, enc_w1, conv_w, pc_w, w1t, Bc1, bij, w2t8);
    hipLaunchKernelGGL(k_c1gemm, dim3(1600), dim3(512), 0, stream, data, Bc1, conv_b, xt8);
    hipLaunchKernelGGL(k_pcgemm, dim3(1152), dim3(256), 0, stream, xt8, w2t8, parts);
    hipLaunchKernelGGL(k_squash, dim3(512), dim3(256), 0, stream, parts, pc_b, ub);
    hipLaunchKernelGGL(k_uT, dim3(1152), dim3(256), 0, stream, ub, uT);
    for (int it = 0; it < 3; ++it) {
        if (it == 0) {
            hipLaunchKernelGGL(k_fold0, dim3(5760), dim3(256), 0, stream, W, cw2T);
        } else {
            hipLaunchKernelGGL(k_cij, dim3(10), dim3(256), 0, stream, bij, cij);
            hipLaunchKernelGGL(k_fold, dim3(5760), dim3(256), 0, stream, cij, W, cw2T);
        }
        // s partials: mtiles=8, ksplit=72, steps=2 -> grid 576
        hipLaunchKernelGGL(k_rgemm, dim3(576), dim3(256), 0, stream, ub, cw2T, sp, 9216, 2, 8);
        hipLaunchKernelGGL(k_vcomp, dim3(320), dim3(256), 0, stream, sp, v, vT);
        if (it < 2) {
            hipLaunchKernelGGL(k_ggemm2, dim3(144), dim3(256), 0, stream, uT, vT, W, bij);
        }
    }
    hipLaunchKernelGGL(k_enc, dim3(128), dim3(256), 0, stream, v, w1t, enc_b1, enc_w2, enc_b2, outp);
}

// Round 14
// 291.114 us; speedup vs baseline: 1.0079x; 1.0079x over previous
//
#include <hip/hip_runtime.h>
#include <hip/hip_bf16.h>
#include <stdint.h>

// CapsNet forward. B=512, conv1 1->256 9x9 s1 (28->20), pc 256->256 9x9 s2 (20->6),
// routes R=1152, caps C=10, I=8, O=16, encoder 160->512->9.
// R14: pcgemm frozen at R12 (BN=128, grid 576 — measured plateau 1565 TF);
// fold fused into rgemm B-staging (k_fold/k_fold0 deleted); k_cij always runs.

typedef __bf16 bf16_t;
typedef __bf16 bf16x4 __attribute__((ext_vector_type(4)));
typedef __bf16 bf16x8 __attribute__((ext_vector_type(8)));
typedef float f32x4 __attribute__((ext_vector_type(4)));
typedef int i32x4 __attribute__((ext_vector_type(4)));
typedef int i32x8 __attribute__((ext_vector_type(8)));

__device__ __forceinline__ void gload_lds16(const void* g, void* l) {
    __builtin_amdgcn_global_load_lds((const __attribute__((address_space(1))) void*)g,
                                     (__attribute__((address_space(3))) void*)l, 16, 0, 0);
}

#define MEMBAR() asm volatile("" ::: "memory")

// f32 -> e4m3 byte (RNE via v_cvt_pk_fp8_f32)
__device__ __forceinline__ uint8_t fp8b(float v) {
    return (uint8_t)(__builtin_amdgcn_cvt_pk_fp8_f32(v, 0.f, 0, false) & 0xFF);
}

// ---------------- merged prep: bij=0, w1t, Bc1, w2t8 ----------------
// blocks: [0,45) bij ; [45,365) w1t ; [365,469) Bc1 ; [469,725) w2t8 (oc = blk-469)
__global__ __launch_bounds__(256) void k_prep(const float* __restrict__ w1,
                                              const float* __restrict__ cw,
                                              const float* __restrict__ pcw,
                                              float* __restrict__ w1t,
                                              bf16_t* __restrict__ Bc1,
                                              float* __restrict__ bij,
                                              uint8_t* __restrict__ w2t8) {
    __shared__ uint16_t tmp16[10368];
    int blk = blockIdx.x, tid = threadIdx.x;
    if (blk < 45) {
        int i = blk * 256 + tid;
        if (i < 11520) bij[i] = 0.f;
    } else if (blk < 365) {
        int i = (blk - 45) * 256 + tid;  // 81920
        int j = i / 160, k = i % 160;
        w1t[k * 512 + j] = w1[i];
    } else if (blk < 469) {
        int i = (blk - 365) * 256 + tid;  // 26624
        if (i < 26624) {
            int oc = i / 104, k = i % 104;
            Bc1[i] = (k < 81) ? (bf16_t)cw[oc * 81 + k] : (bf16_t)0.f;
        }
    } else {
        // pc_w f32 [oc][ic][81] -> w2t8 fp8 [oc][k], k = t*256+ic, value = fp8(pc_w*64)
        int oc = blk - 469;
        const float* src = pcw + (size_t)oc * 20736;
        for (int q2 = tid; q2 < 10368; q2 += 256) {
            float a = src[q2 * 2] * 64.f;
            float b = src[q2 * 2 + 1] * 64.f;
            uint32_t pk = __builtin_amdgcn_cvt_pk_fp8_f32(a, b, 0, false);
            tmp16[q2] = (uint16_t)(pk & 0xFFFF);
        }
        __syncthreads();
        uint32_t* dst = (uint32_t*)(w2t8 + (size_t)oc * 20736);
        for (int w = tid; w < 5184; w += 256) {
            int k = w * 4;
            int t = k >> 8, ic0 = k & 255;
            uint32_t r = 0;
#pragma unroll
            for (int j = 0; j < 4; ++j) {
                int s = (ic0 + j) * 81 + t;
                uint32_t b = (tmp16[s >> 1] >> ((s & 1) * 8)) & 0xFF;
                r |= b << (8 * j);
            }
            dst[w] = r;
        }
    }
}

// ---------------- conv1 as MFMA GEMM, vectorized in-LDS im2col -> xt8 fp8 [m][256] ----------------
// M=204800 (1600 tiles of 128), N=256, K=96 (3 kk). grid 1600; 8 waves (2m x 4n).
__global__ __launch_bounds__(512) void k_c1gemm(const float* __restrict__ data,
                                                const bf16_t* __restrict__ Bc1,
                                                const float* __restrict__ cb,
                                                uint8_t* __restrict__ xt8) {
    __shared__ __align__(16) bf16_t As[128 * 104];  // 26,624 B
    __shared__ __align__(16) bf16_t Bs[256 * 104];  // 53,248 B
    int tid = threadIdx.x, lane = tid & 63, wave = tid >> 6;
    int wm = wave >> 2, wn = wave & 3;
    for (int i = tid; i < 3328; i += 512) {
        int byte = i * 16;
        int r = byte / 208;
        int c16 = (byte - r * 208) >> 4;
        gload_lds16(Bc1 + r * 104 + c16 * 8, (char*)Bs + byte);
    }
    int mr = wm * 64 + (lane & 15);
    int nr = wn * 64 + (lane & 15);
    float bias[4];
#pragma unroll
    for (int nj = 0; nj < 4; ++nj) bias[nj] = cb[nr + nj * 16];

    int m0 = blockIdx.x * 128;
    for (int z = tid; z < 128 * 23; z += 512) {
        int r = z / 23, k = 81 + z - (z / 23) * 23;
        As[r * 104 + k] = (bf16_t)0.f;
    }
    for (int pr = tid; pr < 1152; pr += 512) {
        int r = pr / 9, kh = pr - (pr / 9) * 9;
        int m = m0 + r;
        int b = m / 400, pos = m - b * 400;
        int oh = pos / 20, ow = pos - oh * 20;
        const float* src = data + (size_t)b * 784 + (oh + kh) * 28 + ow;
        bf16_t* dst = &As[r * 104 + kh * 9];
#pragma unroll
        for (int j = 0; j < 9; ++j) dst[j] = (bf16_t)src[j];
    }
    asm volatile("s_waitcnt vmcnt(0)" ::: "memory");
    __syncthreads();
    f32x4 acc[4][4];
#pragma unroll
    for (int mi = 0; mi < 4; ++mi)
#pragma unroll
        for (int nj = 0; nj < 4; ++nj) acc[mi][nj] = (f32x4){0.f, 0.f, 0.f, 0.f};
#pragma unroll
    for (int kk = 0; kk < 3; ++kk) {
        int ch = (kk * 4 + (lane >> 4)) * 8;
        bf16x8 af[4], bfr[4];
#pragma unroll
        for (int i = 0; i < 4; ++i) af[i] = *(const bf16x8*)&As[(mr + i * 16) * 104 + ch];
#pragma unroll
        for (int j = 0; j < 4; ++j) bfr[j] = *(const bf16x8*)&Bs[(nr + j * 16) * 104 + ch];
#pragma unroll
        for (int mi = 0; mi < 4; ++mi)
#pragma unroll
            for (int nj = 0; nj < 4; ++nj)
                acc[mi][nj] = __builtin_amdgcn_mfma_f32_16x16x32_bf16(af[mi], bfr[nj], acc[mi][nj], 0, 0, 0);
    }
    int mbase = m0 + wm * 64 + (lane >> 4) * 4;
#pragma unroll
    for (int mi = 0; mi < 4; ++mi)
#pragma unroll
        for (int nj = 0; nj < 4; ++nj)
#pragma unroll
            for (int j = 0; j < 4; ++j)
                xt8[(size_t)(mbase + mi * 16 + j) * 256 + nr + nj * 16] =
                    fp8b(fmaxf(acc[mi][nj][j] + bias[nj], 0.f));
}

// ---------------- PrimaryCaps implicit GEMM, MX-fp8 (R12-frozen: BN=128, grid 576) ----------------
// grid 576 = 144 m-tiles x 2 n-tiles x 2 k-splits ; tile 128x128, BK=128 B, 81 steps.
// Scales: A = 2^0 (0x7F), B = 2^-6 (0x79, undoes the x64 in w2t8).
__global__ __launch_bounds__(256) void k_pcgemm(const uint8_t* __restrict__ xt8,
                                                const uint8_t* __restrict__ w2t8,
                                                bf16_t* __restrict__ parts) {
    __shared__ __align__(16) uint8_t As[128 * 128];
    __shared__ __align__(16) uint8_t Bs[128 * 128];
    int bid = blockIdx.x;
    int mt = bid % 144;
    int nt = (bid / 144) & 1;
    int ks = bid / 288;  // 0..1
    int m0 = mt * 128, n0 = nt * 128;
    int tid = threadIdx.x, lane = tid & 63, wave = tid >> 6;

    int csrc = (tid & 7) ^ ((tid >> 3) & 7);  // swizzled source chunk (16-B units)
    int arow[4];
#pragma unroll
    for (int p = 0; p < 4; ++p) {
        int m = m0 + p * 32 + (tid >> 3);
        int bb = m / 36, pos = m % 36;
        int oh = pos / 6, ow = pos % 6;
        arow[p] = ((bb * 20 + oh * 2) * 20 + ow * 2) * 256;
    }
    const uint8_t* bbase = w2t8 + (size_t)(n0 + (tid >> 3)) * 20736 + csrc * 16;

    f32x4 acc[4][4];
#pragma unroll
    for (int mi = 0; mi < 4; ++mi)
#pragma unroll
        for (int ni = 0; ni < 4; ++ni) acc[mi][ni] = (f32x4){0.f, 0.f, 0.f, 0.f};

    int g0 = ks * 81;
    int mr = (wave >> 1) * 64 + (lane & 15);
    int nr = (wave & 1) * 64 + (lane & 15);
    int rx = lane & 7;
    int c0 = (2 * (lane >> 4)) ^ rx;
    int c1 = (2 * (lane >> 4) + 1) ^ rx;

    for (int it = 0; it < 81; ++it) {
        int g = g0 + it;
        int t = g >> 1, icb = g & 1;
        int kh = t / 9, kw = t - (t / 9) * 9;
        int aoff = (kh * 20 + kw) * 256 + icb * 128 + csrc * 16;
#pragma unroll
        for (int p = 0; p < 4; ++p) {
            gload_lds16(xt8 + arow[p] + aoff, &As[p * 4096 + tid * 16]);
            gload_lds16(bbase + (size_t)p * 32 * 20736 + (size_t)g * 128, &Bs[p * 4096 + tid * 16]);
        }
        __syncthreads();
        i32x8 af[4], bfr[4];
#pragma unroll
        for (int i = 0; i < 4; ++i) {
            i32x4 lo = *(const i32x4*)&As[(mr + i * 16) * 128 + c0 * 16];
            i32x4 hi = *(const i32x4*)&As[(mr + i * 16) * 128 + c1 * 16];
            af[i][0] = lo[0]; af[i][1] = lo[1]; af[i][2] = lo[2]; af[i][3] = lo[3];
            af[i][4] = hi[0]; af[i][5] = hi[1]; af[i][6] = hi[2]; af[i][7] = hi[3];
        }
#pragma unroll
        for (int i = 0; i < 4; ++i) {
            i32x4 lo = *(const i32x4*)&Bs[(nr + i * 16) * 128 + c0 * 16];
            i32x4 hi = *(const i32x4*)&Bs[(nr + i * 16) * 128 + c1 * 16];
            bfr[i][0] = lo[0]; bfr[i][1] = lo[1]; bfr[i][2] = lo[2]; bfr[i][3] = lo[3];
            bfr[i][4] = hi[0]; bfr[i][5] = hi[1]; bfr[i][6] = hi[2]; bfr[i][7] = hi[3];
        }
#pragma unroll
        for (int mi = 0; mi < 4; ++mi)
#pragma unroll
            for (int ni = 0; ni < 4; ++ni)
                acc[mi][ni] = __builtin_amdgcn_mfma_scale_f32_16x16x128_f8f6f4(
                    af[mi], bfr[ni], acc[mi][ni], 0, 0, 0, 0x7F7F7F7F, 0, 0x79797979);
        __syncthreads();
    }

    bf16_t* out = parts + (size_t)ks * 4718592;
    int mbase = m0 + (wave >> 1) * 64 + (lane >> 4) * 4;
    int nbase = n0 + (wave & 1) * 64 + (lane & 15);
#pragma unroll
    for (int mi = 0; mi < 4; ++mi)
#pragma unroll
        for (int ni = 0; ni < 4; ++ni)
#pragma unroll
            for (int j = 0; j < 4; ++j)
                out[(size_t)(mbase + mi * 16 + j) * 256 + nbase + ni * 16] = (bf16_t)acc[mi][ni][j];
}

// ---------------- squash -> u bf16 [b][flat], flat = oc*36+pos ----------------
__global__ __launch_bounds__(256) void k_squash(const bf16_t* __restrict__ parts,
                                                const float* __restrict__ pcb,
                                                bf16_t* __restrict__ ub) {
    __shared__ float s[36 * 257];
    int b = blockIdx.x, tid = threadIdx.x;
    for (int i = tid; i < 9216; i += 256) {
        float a = pcb[i & 255];
#pragma unroll
        for (int p = 0; p < 2; ++p) a += (float)parts[(size_t)p * 4718592 + (size_t)b * 9216 + i];
        s[(i >> 8) * 257 + (i & 255)] = a;
    }
    __syncthreads();
    for (int r = tid; r < 1152; r += 256) {
        int flat0 = r * 8;
        float val[8], sn = 0.f;
#pragma unroll
        for (int e = 0; e < 8; ++e) {
            int f = flat0 + e;
            float x = s[(f % 36) * 257 + f / 36];
            val[e] = x;
            sn += x * x;
        }
        float scale = sn / ((1.f + sn) * sqrtf(sn));
        bf16x8 vv;
#pragma unroll
        for (int e = 0; e < 8; ++e) vv[e] = (bf16_t)(val[e] * scale);
        *(bf16x8*)&ub[(size_t)b * 9216 + flat0] = vv;
    }
}

// ---------------- u bf16 [512][9216] -> uT bf16 [9216][512] ----------------
__global__ __launch_bounds__(256) void k_uT(const bf16_t* __restrict__ ub, bf16_t* __restrict__ uT) {
    __shared__ bf16_t t[64 * 66];
    int kt = blockIdx.x % 144, bt = blockIdx.x / 144;
    int k0 = kt * 64, b0 = bt * 64;
    int tid = threadIdx.x;
    int c8 = tid & 7;
#pragma unroll
    for (int p = 0; p < 2; ++p) {
        int r = p * 32 + (tid >> 3);  // b-local
        bf16x8 vv = *(const bf16x8*)&ub[(size_t)(b0 + r) * 9216 + k0 + c8 * 8];
        uint32_t u4[4];
        *(bf16x8*)u4 = vv;
#pragma unroll
        for (int j2 = 0; j2 < 4; ++j2)
            *(uint32_t*)&t[r * 66 + c8 * 8 + j2 * 2] = u4[j2];
    }
    __syncthreads();
#pragma unroll
    for (int p = 0; p < 2; ++p) {
        int kp = p * 32 + (tid >> 3);  // k-local
        bf16x8 vv;
#pragma unroll
        for (int j = 0; j < 8; ++j) vv[j] = t[(c8 * 8 + j) * 66 + kp];
        *(bf16x8*)&uT[(size_t)(k0 + kp) * 512 + b0 + c8 * 8] = vv;
    }
}

// ---------------- cij = softmax_r(bij) per caps column (10 blocks) ----------------
// iter0: bij = 0 -> cij = 1/1152 exactly (no special case needed).
__global__ void k_cij(const float* __restrict__ bij, float* __restrict__ cij) {
    __shared__ float red[256];
    int c = blockIdx.x, tid = threadIdx.x;
    float mx = -1e30f;
    for (int r = tid; r < 1152; r += 256) mx = fmaxf(mx, bij[r * 10 + c]);
    red[tid] = mx; __syncthreads();
    for (int s = 128; s > 0; s >>= 1) { if (tid < s) red[tid] = fmaxf(red[tid], red[tid + s]); __syncthreads(); }
    float MX = red[0]; __syncthreads();
    float sm = 0.f;
    for (int r = tid; r < 1152; r += 256) sm += expf(bij[r * 10 + c] - MX);
    red[tid] = sm; __syncthreads();
    for (int s = 128; s > 0; s >>= 1) { if (tid < s) red[tid] += red[tid + s]; __syncthreads(); }
    float inv = 1.f / red[0];
    for (int r = tid; r < 1152; r += 256) cij[r * 10 + c] = expf(bij[r * 10 + c] - MX) * inv;
}

// ---------------- s-GEMM with FUSED fold: sp[ks][M][160] = A[M][K] x (cij.W)[160][K]^T ----------------
// B element for row co=16c+o, col k=8*kr+i: cij[kr*10+c] * W[(kr*10+c)*128 + o*8 + i].
// A thread's 8-k chunk shares one (kr,c): 1 scalar cij + 2 f32x4 W loads + 1 ds_write_b128.
// grid = mtiles * ksplit (8 x 36 = 288), steps=4.
__global__ __launch_bounds__(256) void k_rgemm(const bf16_t* __restrict__ A,
                                               const float* __restrict__ W,
                                               const float* __restrict__ cij,
                                               bf16_t* __restrict__ Cp,
                                               int Kfull, int steps, int mtiles) {
    __shared__ __align__(16) bf16_t As[64 * 64];
    __shared__ __align__(16) bf16_t Bs[160 * 64];
    int bid = blockIdx.x;
    int mt = bid % mtiles, ks = bid / mtiles;
    int m0 = mt * 64;
    int k0 = ks * steps * 64;
    int tid = threadIdx.x, lane = tid & 63, wave = tid >> 6;
    int srow = tid >> 3;                       // 0..31
    int csrc = (tid & 7) ^ (srow & 7);
    const bf16_t* asrc[2];
#pragma unroll
    for (int p = 0; p < 2; ++p)
        asrc[p] = A + (size_t)(m0 + p * 32 + srow) * Kfull + k0 + csrc * 8;
    int co_c[5], co_o[5];
#pragma unroll
    for (int p = 0; p < 5; ++p) {
        int co = p * 32 + srow;
        co_c[p] = co >> 4;
        co_o[p] = co & 15;
    }

    f32x4 acc[2][5];
#pragma unroll
    for (int mi = 0; mi < 2; ++mi)
#pragma unroll
        for (int nj = 0; nj < 5; ++nj) acc[mi][nj] = (f32x4){0.f, 0.f, 0.f, 0.f};

    int mr = (wave >> 1) * 32 + (lane & 15);
    int nr = (wave & 1) * 80 + (lane & 15);
    int rx = lane & 7;

    for (int it = 0; it < steps; ++it) {
#pragma unroll
        for (int p = 0; p < 2; ++p) gload_lds16(asrc[p] + it * 64, As + p * 2048 + tid * 8);
        // fused fold: compute B chunk (8 bf16) from cij & W, write to LDS
        int kr = (k0 >> 3) + it * 8 + csrc;
#pragma unroll
        for (int p = 0; p < 5; ++p) {
            int rc = kr * 10 + co_c[p];
            float cv = cij[rc];
            const float* wp = W + ((size_t)rc << 7) + co_o[p] * 8;
            f32x4 w0 = *(const f32x4*)wp;
            f32x4 w1 = *(const f32x4*)(wp + 4);
            bf16x8 bb;
            bb[0] = (bf16_t)(cv * w0.x); bb[1] = (bf16_t)(cv * w0.y);
            bb[2] = (bf16_t)(cv * w0.z); bb[3] = (bf16_t)(cv * w0.w);
            bb[4] = (bf16_t)(cv * w1.x); bb[5] = (bf16_t)(cv * w1.y);
            bb[6] = (bf16_t)(cv * w1.z); bb[7] = (bf16_t)(cv * w1.w);
            *(bf16x8*)&Bs[p * 2048 + tid * 8] = bb;
        }
        __syncthreads();
#pragma unroll
        for (int kk = 0; kk < 2; ++kk) {
            int ch = ((kk * 4 + (lane >> 4)) ^ rx) * 8;
            bf16x8 af[2], bfr[5];
#pragma unroll
            for (int i = 0; i < 2; ++i) af[i] = *(const bf16x8*)&As[(mr + i * 16) * 64 + ch];
#pragma unroll
            for (int j = 0; j < 5; ++j) bfr[j] = *(const bf16x8*)&Bs[(nr + j * 16) * 64 + ch];
#pragma unroll
            for (int mi = 0; mi < 2; ++mi)
#pragma unroll
                for (int nj = 0; nj < 5; ++nj)
                    acc[mi][nj] = __builtin_amdgcn_mfma_f32_16x16x32_bf16(af[mi], bfr[nj], acc[mi][nj], 0, 0, 0);
        }
        __syncthreads();
    }

    bf16_t* out = Cp + (size_t)ks * ((size_t)mtiles * 64 * 160);
    int mbase = m0 + (wave >> 1) * 32 + (lane >> 4) * 4;
    int nbase = (wave & 1) * 80 + (lane & 15);
#pragma unroll
    for (int mi = 0; mi < 2; ++mi)
#pragma unroll
        for (int nj = 0; nj < 5; ++nj)
#pragma unroll
            for (int j = 0; j < 4; ++j)
                out[(size_t)(mbase + mi * 16 + j) * 160 + nbase + nj * 16] = (bf16_t)acc[mi][nj][j];
}

// ---------------- v + vT from bf16 s partials (36 splits) ----------------
__global__ void k_vcomp(const bf16_t* __restrict__ sp, float* __restrict__ v,
                        bf16_t* __restrict__ vT) {
    int idx = blockIdx.x * 256 + threadIdx.x;  // 81920
    float s = 0.f;
#pragma unroll
    for (int p = 0; p < 36; ++p) s += (float)sp[(size_t)p * 81920 + idx];
    float val = s * fabsf(s) / (1.f + s * s);
    v[idx] = val;
    int b = idx / 160, co = idx % 160;
    vT[(size_t)co * 512 + b] = (bf16_t)val;
}

// ---------------- G-gemm + amean fused ----------------
__global__ __launch_bounds__(256) void k_ggemm2(const bf16_t* __restrict__ uT,
                                                const bf16_t* __restrict__ vT,
                                                const float* __restrict__ W,
                                                float* __restrict__ bij) {
    __shared__ __align__(16) bf16_t As[64 * 64];
    __shared__ __align__(16) bf16_t Bs[160 * 64];
    __shared__ float Gl[64 * 161];
    int mt = blockIdx.x;
    int m0 = mt * 64;
    int tid = threadIdx.x, lane = tid & 63, wave = tid >> 6;
    int srow = tid >> 3;
    int csrc = (tid & 7) ^ (srow & 7);
    const bf16_t* asrc[2];
    const bf16_t* bsrc[5];
#pragma unroll
    for (int p = 0; p < 2; ++p)
        asrc[p] = uT + (size_t)(m0 + p * 32 + srow) * 512 + csrc * 8;
#pragma unroll
    for (int p = 0; p < 5; ++p)
        bsrc[p] = vT + (size_t)(p * 32 + srow) * 512 + csrc * 8;

    f32x4 acc[2][5];
#pragma unroll
    for (int mi = 0; mi < 2; ++mi)
#pragma unroll
        for (int nj = 0; nj < 5; ++nj) acc[mi][nj] = (f32x4){0.f, 0.f, 0.f, 0.f};

    int mr = (wave >> 1) * 32 + (lane & 15);
    int nr = (wave & 1) * 80 + (lane & 15);
    int rx = lane & 7;

    for (int it = 0; it < 8; ++it) {
#pragma unroll
        for (int p = 0; p < 2; ++p) gload_lds16(asrc[p] + it * 64, As + p * 2048 + tid * 8);
#pragma unroll
        for (int p = 0; p < 5; ++p) gload_lds16(bsrc[p] + it * 64, Bs + p * 2048 + tid * 8);
        __syncthreads();
#pragma unroll
        for (int kk = 0; kk < 2; ++kk) {
            int ch = ((kk * 4 + (lane >> 4)) ^ rx) * 8;
            bf16x8 af[2], bfr[5];
#pragma unroll
            for (int i = 0; i < 2; ++i) af[i] = *(const bf16x8*)&As[(mr + i * 16) * 64 + ch];
#pragma unroll
            for (int j = 0; j < 5; ++j) bfr[j] = *(const bf16x8*)&Bs[(nr + j * 16) * 64 + ch];
#pragma unroll
            for (int mi = 0; mi < 2; ++mi)
#pragma unroll
                for (int nj = 0; nj < 5; ++nj)
                    acc[mi][nj] = __builtin_amdgcn_mfma_f32_16x16x32_bf16(af[mi], bfr[nj], acc[mi][nj], 0, 0, 0);
        }
        __syncthreads();
    }

    int mbl = (wave >> 1) * 32 + (lane >> 4) * 4;
    int nbase = (wave & 1) * 80 + (lane & 15);
#pragma unroll
    for (int mi = 0; mi < 2; ++mi)
#pragma unroll
        for (int nj = 0; nj < 5; ++nj)
#pragma unroll
            for (int j = 0; j < 4; ++j)
                Gl[(mbl + mi * 16 + j) * 161 + nbase + nj * 16] = acc[mi][nj][j] * (1.0f / 512.0f);
    __syncthreads();
    if (tid < 80) {
        int rl = tid / 10, c = tid % 10;
        int r = mt * 8 + rl;
        const float* wbase = W + (size_t)(r * 10 + c) * 128;
        float s = 0.f;
#pragma unroll
        for (int o = 0; o < 16; ++o)
#pragma unroll
            for (int i = 0; i < 8; ++i)
                s += wbase[o * 8 + i] * Gl[(rl * 8 + i) * 161 + c * 16 + o];
        bij[r * 10 + c] += s;
    }
}

// ---------------- encoder, 4 images per block (grid 128) ----------------
__global__ __launch_bounds__(256) void k_enc(const float* __restrict__ v,
                                             const float* __restrict__ w1t,
                                             const float* __restrict__ b1,
                                             const float* __restrict__ w2,
                                             const float* __restrict__ b2,
                                             float* __restrict__ out) {
    __shared__ float fl[4 * 160];
    __shared__ float h[4 * 512];
    int b0 = blockIdx.x * 4, tid = threadIdx.x;
    for (int i = tid; i < 640; i += 256) fl[i] = v[(size_t)b0 * 160 + i];
    __syncthreads();
    for (int j = tid; j < 512; j += 256) {
        float bb = b1[j];
        float a0 = bb, a1 = bb, a2 = bb, a3 = bb;
        for (int k = 0; k < 160; ++k) {
            float w = w1t[k * 512 + j];
            a0 += fl[k] * w;
            a1 += fl[160 + k] * w;
            a2 += fl[320 + k] * w;
            a3 += fl[480 + k] * w;
        }
        h[j] = fmaxf(a0, 0.f);
        h[512 + j] = fmaxf(a1, 0.f);
        h[1024 + j] = fmaxf(a2, 0.f);
        h[1536 + j] = fmaxf(a3, 0.f);
    }
    __syncthreads();
    int wave = tid >> 6, lane = tid & 63;
    int q = wave;  // image 0..3
    for (int j = 0; j < 9; ++j) {
        float p = 0.f;
#pragma unroll
        for (int l = lane; l < 512; l += 64) p += h[q * 512 + l] * w2[j * 512 + l];
#pragma unroll
        for (int off = 32; off > 0; off >>= 1) p += __shfl_down(p, off, 64);
        if (lane == 0) out[(b0 + q) * 9 + j] = 1.f / (1.f + expf(-(p + b2[j])));
    }
}

// ---------------- launch ----------------
extern "C" void kernel_launch(void* const* d_in, const int* in_sizes, int n_in,
                              void* d_out, int out_size, void* d_ws, size_t ws_size,
                              hipStream_t stream) {
    const float* data   = (const float*)d_in[0];
    const float* conv_w = (const float*)d_in[1];
    const float* conv_b = (const float*)d_in[2];
    const float* pc_w   = (const float*)d_in[3];
    const float* pc_b   = (const float*)d_in[4];
    const float* W      = (const float*)d_in[5];
    const float* enc_w1 = (const float*)d_in[6];
    const float* enc_b1 = (const float*)d_in[7];
    const float* enc_w2 = (const float*)d_in[8];
    const float* enc_b2 = (const float*)d_in[9];

    char* ws = (char*)d_ws;
    uint8_t* xt8   = (uint8_t*)(ws + 0);           //  52,428,800
    uint8_t* w2t8  = (uint8_t*)(ws + 52428800);    //   5,308,416 ->  57,737,216
    bf16_t*  parts = (bf16_t*)(ws + 57737216);     //  18,874,368 (2 x 9,437,184 B) -> 76,611,584
    bf16_t*  uT    = (bf16_t*)(ws + 76611584);     //   9,437,184 ->  86,048,768
    bf16_t*  sp    = (bf16_t*)(ws + 86048768);     //   5,898,240 (36 x 163,840 B) -> 91,947,008
    bf16_t*  ub    = (bf16_t*)(ws + 91947008);     //   9,437,184 -> 101,384,192
    float*   v     = (float*)(ws + 101384192);     //     327,680 -> 101,711,872
    bf16_t*  vT    = (bf16_t*)(ws + 101711872);    //     163,840 -> 101,875,712
    float*   w1t   = (float*)(ws + 101875712);     //     327,680 -> 102,203,392
    float*   bij   = (float*)(ws + 102203392);     //      46,080 -> 102,249,472
    float*   cij   = (float*)(ws + 102249472);     //      46,080 -> 102,295,552
    bf16_t*  Bc1   = (bf16_t*)(ws + 102295552);    //      53,248 -> 102,348,800 total
    float*   outp  = (float*)d_out;

    hipLaunchKernelGGL(k_prep, dim3(725), dim3(256), 0, stream, enc_w1, conv_w, pc_w, w1t, Bc1, bij, w2t8);
    hipLaunchKernelGGL(k_c1gemm, dim3(1600), dim3(512), 0, stream, data, Bc1, conv_b, xt8);
    hipLaunchKernelGGL(k_pcgemm, dim3(576), dim3(256), 0, stream, xt8, w2t8, parts);
    hipLaunchKernelGGL(k_squash, dim3(512), dim3(256), 0, stream, parts, pc_b, ub);
    hipLaunchKernelGGL(k_uT, dim3(1152), dim3(256), 0, stream, ub, uT);
    for (int it = 0; it < 3; ++it) {
        hipLaunchKernelGGL(k_cij, dim3(10), dim3(256), 0, stream, bij, cij);
        // s partials: mtiles=8, ksplit=36, steps=4 -> grid 288 (fold fused into B-staging)
        hipLaunchKernelGGL(k_rgemm, dim3(288), dim3(256), 0, stream, ub, W, cij, sp, 9216, 4, 8);
        hipLaunchKernelGGL(k_vcomp, dim3(320), dim3(256), 0, stream, sp, v, vT);
        if (it < 2) {
            hipLaunchKernelGGL(k_ggemm2, dim3(144), dim3(256), 0, stream, uT, vT, W, bij);
        }
    }
    hipLaunchKernelGGL(k_enc, dim3(128), dim3(256), 0, stream, v, w1t, enc_b1, enc_w2, enc_b2, outp);
}

// Round 15
// 286.324 us; speedup vs baseline: 1.0247x; 1.0167x over previous
//
#include <hip/hip_runtime.h>
#include <hip/hip_bf16.h>
#include <stdint.h>

// CapsNet forward. B=512, conv1 1->256 9x9 s1 (28->20), pc 256->256 9x9 s2 (20->6),
// routes R=1152, caps C=10, I=8, O=16, encoder 160->512->9.
// R15: restore R12 verbatim — the measured-best configuration (286.6 us).
// pcgemm: MX-fp8 single-buffer, BN=128, grid 576 (structural plateau, 1565 TF).
// Tail: separate fold0/cij+fold, rgemm ksplit=36, c1gemm 2-tile loop, 1-image enc.

typedef __bf16 bf16_t;
typedef __bf16 bf16x4 __attribute__((ext_vector_type(4)));
typedef __bf16 bf16x8 __attribute__((ext_vector_type(8)));
typedef float f32x4 __attribute__((ext_vector_type(4)));
typedef int i32x4 __attribute__((ext_vector_type(4)));
typedef int i32x8 __attribute__((ext_vector_type(8)));

__device__ __forceinline__ void gload_lds16(const void* g, void* l) {
    __builtin_amdgcn_global_load_lds((const __attribute__((address_space(1))) void*)g,
                                     (__attribute__((address_space(3))) void*)l, 16, 0, 0);
}

#define MEMBAR() asm volatile("" ::: "memory")

// f32 -> e4m3 byte (RNE via v_cvt_pk_fp8_f32)
__device__ __forceinline__ uint8_t fp8b(float v) {
    return (uint8_t)(__builtin_amdgcn_cvt_pk_fp8_f32(v, 0.f, 0, false) & 0xFF);
}

// ---------------- merged prep: bij=0, w1t, Bc1 ----------------
__global__ void k_prep(const float* __restrict__ w1, const float* __restrict__ cw,
                       float* __restrict__ w1t, bf16_t* __restrict__ Bc1,
                       float* __restrict__ bij) {
    int blk = blockIdx.x, tid = threadIdx.x;
    if (blk < 45) {
        int i = blk * 256 + tid;
        if (i < 11520) bij[i] = 0.f;
    } else if (blk < 365) {
        int i = (blk - 45) * 256 + tid;  // 81920
        int j = i / 160, k = i % 160;
        w1t[k * 512 + j] = w1[i];
    } else {
        int i = (blk - 365) * 256 + tid;  // 26624
        if (i < 26624) {
            int oc = i / 104, k = i % 104;
            Bc1[i] = (k < 81) ? (bf16_t)cw[oc * 81 + k] : (bf16_t)0.f;
        }
    }
}

// pc_w f32 [oc][ic][81] -> w2t8 fp8 [oc][k], k = t*256 + ic, value = fp8(pc_w * 64)
__global__ __launch_bounds__(256) void k_w2t(const float* __restrict__ pcw,
                                             uint8_t* __restrict__ w2t8) {
    __shared__ uint16_t tmp16[10368];  // fp8 pairs in SOURCE order (ic*81+t)
    int oc = blockIdx.x, tid = threadIdx.x;
    const float* src = pcw + (size_t)oc * 20736;
    for (int q2 = tid; q2 < 10368; q2 += 256) {
        float a = src[q2 * 2] * 64.f;
        float b = src[q2 * 2 + 1] * 64.f;
        uint32_t pk = __builtin_amdgcn_cvt_pk_fp8_f32(a, b, 0, false);
        tmp16[q2] = (uint16_t)(pk & 0xFFFF);
    }
    __syncthreads();
    uint32_t* dst = (uint32_t*)(w2t8 + (size_t)oc * 20736);
    for (int w = tid; w < 5184; w += 256) {  // out word = k 4w..4w+3
        int k = w * 4;
        int t = k >> 8, ic0 = k & 255;
        uint32_t r = 0;
#pragma unroll
        for (int j = 0; j < 4; ++j) {
            int s = (ic0 + j) * 81 + t;
            uint32_t b = (tmp16[s >> 1] >> ((s & 1) * 8)) & 0xFF;
            r |= b << (8 * j);
        }
        dst[w] = r;
    }
}

// ---------------- conv1 as MFMA GEMM, vectorized in-LDS im2col -> xt8 fp8 [m][256] ----------------
// M=204800, N=256, K=96 (3 kk, pad 81..95=0). grid 800 x 2 m-tiles; 8 waves (2m x 4n).
// LDS = As 26,624 + Bs 53,248 = 79,872 B <= 80 KiB -> 2 blocks/CU.
__global__ __launch_bounds__(512) void k_c1gemm(const float* __restrict__ data,
                                                const bf16_t* __restrict__ Bc1,
                                                const float* __restrict__ cb,
                                                uint8_t* __restrict__ xt8) {
    __shared__ __align__(16) bf16_t As[128 * 104];  // 26,624 B
    __shared__ __align__(16) bf16_t Bs[256 * 104];  // 53,248 B
    int tid = threadIdx.x, lane = tid & 63, wave = tid >> 6;
    int wm = wave >> 2, wn = wave & 3;
    for (int i = tid; i < 3328; i += 512) {
        int byte = i * 16;
        int r = byte / 208;
        int c16 = (byte - r * 208) >> 4;
        gload_lds16(Bc1 + r * 104 + c16 * 8, (char*)Bs + byte);
    }
    int mr = wm * 64 + (lane & 15);
    int nr = wn * 64 + (lane & 15);
    float bias[4];
#pragma unroll
    for (int nj = 0; nj < 4; ++nj) bias[nj] = cb[nr + nj * 16];

    for (int t = 0; t < 2; ++t) {
        int m0 = (blockIdx.x + t * 800) * 128;
        __syncthreads();  // protect As/Bs from prev-iter readers
        // zero the pad columns 81..103
        for (int z = tid; z < 128 * 23; z += 512) {
            int r = z / 23, k = 81 + z - (z / 23) * 23;
            As[r * 104 + k] = (bf16_t)0.f;
        }
        // fill: (row, kh) pairs, 9 contiguous floats each
        for (int pr = tid; pr < 1152; pr += 512) {
            int r = pr / 9, kh = pr - (pr / 9) * 9;
            int m = m0 + r;
            int b = m / 400, pos = m - b * 400;
            int oh = pos / 20, ow = pos - oh * 20;
            const float* src = data + (size_t)b * 784 + (oh + kh) * 28 + ow;
            bf16_t* dst = &As[r * 104 + kh * 9];
#pragma unroll
            for (int j = 0; j < 9; ++j) dst[j] = (bf16_t)src[j];
        }
        asm volatile("s_waitcnt vmcnt(0)" ::: "memory");  // Bs gload drained (t=0)
        __syncthreads();  // As ready
        f32x4 acc[4][4];
#pragma unroll
        for (int mi = 0; mi < 4; ++mi)
#pragma unroll
            for (int nj = 0; nj < 4; ++nj) acc[mi][nj] = (f32x4){0.f, 0.f, 0.f, 0.f};
#pragma unroll
        for (int kk = 0; kk < 3; ++kk) {
            int ch = (kk * 4 + (lane >> 4)) * 8;
            bf16x8 af[4], bfr[4];
#pragma unroll
            for (int i = 0; i < 4; ++i) af[i] = *(const bf16x8*)&As[(mr + i * 16) * 104 + ch];
#pragma unroll
            for (int j = 0; j < 4; ++j) bfr[j] = *(const bf16x8*)&Bs[(nr + j * 16) * 104 + ch];
#pragma unroll
            for (int mi = 0; mi < 4; ++mi)
#pragma unroll
                for (int nj = 0; nj < 4; ++nj)
                    acc[mi][nj] = __builtin_amdgcn_mfma_f32_16x16x32_bf16(af[mi], bfr[nj], acc[mi][nj], 0, 0, 0);
        }
        int mbase = m0 + wm * 64 + (lane >> 4) * 4;
#pragma unroll
        for (int mi = 0; mi < 4; ++mi)
#pragma unroll
            for (int nj = 0; nj < 4; ++nj)
#pragma unroll
                for (int j = 0; j < 4; ++j)
                    xt8[(size_t)(mbase + mi * 16 + j) * 256 + nr + nj * 16] =
                        fp8b(fmaxf(acc[mi][nj][j] + bias[nj], 0.f));
    }
}

// ---------------- PrimaryCaps implicit GEMM, MX-fp8 (measured plateau: BN=128, grid 576) ----------------
// grid 576 = 144 m-tiles x 2 n-tiles x 2 k-splits ; tile 128x128, BK=128 B, 81 steps.
// Scales: A = 2^0 (0x7F), B = 2^-6 (0x79, undoes the x64 in w2t8).
__global__ __launch_bounds__(256) void k_pcgemm(const uint8_t* __restrict__ xt8,
                                                const uint8_t* __restrict__ w2t8,
                                                bf16_t* __restrict__ parts) {
    __shared__ __align__(16) uint8_t As[128 * 128];
    __shared__ __align__(16) uint8_t Bs[128 * 128];
    int bid = blockIdx.x;
    int mt = bid % 144;
    int nt = (bid / 144) & 1;
    int ks = bid / 288;  // 0..1
    int m0 = mt * 128, n0 = nt * 128;
    int tid = threadIdx.x, lane = tid & 63, wave = tid >> 6;

    int csrc = (tid & 7) ^ ((tid >> 3) & 7);  // swizzled source chunk (16-B units)
    int arow[4];
#pragma unroll
    for (int p = 0; p < 4; ++p) {
        int m = m0 + p * 32 + (tid >> 3);
        int bb = m / 36, pos = m % 36;
        int oh = pos / 6, ow = pos % 6;
        arow[p] = ((bb * 20 + oh * 2) * 20 + ow * 2) * 256;
    }
    const uint8_t* bbase = w2t8 + (size_t)(n0 + (tid >> 3)) * 20736 + csrc * 16;

    f32x4 acc[4][4];
#pragma unroll
    for (int mi = 0; mi < 4; ++mi)
#pragma unroll
        for (int ni = 0; ni < 4; ++ni) acc[mi][ni] = (f32x4){0.f, 0.f, 0.f, 0.f};

    int g0 = ks * 81;
    int mr = (wave >> 1) * 64 + (lane & 15);
    int nr = (wave & 1) * 64 + (lane & 15);
    int rx = lane & 7;
    int c0 = (2 * (lane >> 4)) ^ rx;
    int c1 = (2 * (lane >> 4) + 1) ^ rx;

    for (int it = 0; it < 81; ++it) {
        int g = g0 + it;
        int t = g >> 1, icb = g & 1;
        int kh = t / 9, kw = t - (t / 9) * 9;
        int aoff = (kh * 20 + kw) * 256 + icb * 128 + csrc * 16;
#pragma unroll
        for (int p = 0; p < 4; ++p) {
            gload_lds16(xt8 + arow[p] + aoff, &As[p * 4096 + tid * 16]);
            gload_lds16(bbase + (size_t)p * 32 * 20736 + (size_t)g * 128, &Bs[p * 4096 + tid * 16]);
        }
        __syncthreads();
        i32x8 af[4], bfr[4];
#pragma unroll
        for (int i = 0; i < 4; ++i) {
            i32x4 lo = *(const i32x4*)&As[(mr + i * 16) * 128 + c0 * 16];
            i32x4 hi = *(const i32x4*)&As[(mr + i * 16) * 128 + c1 * 16];
            af[i][0] = lo[0]; af[i][1] = lo[1]; af[i][2] = lo[2]; af[i][3] = lo[3];
            af[i][4] = hi[0]; af[i][5] = hi[1]; af[i][6] = hi[2]; af[i][7] = hi[3];
        }
#pragma unroll
        for (int i = 0; i < 4; ++i) {
            i32x4 lo = *(const i32x4*)&Bs[(nr + i * 16) * 128 + c0 * 16];
            i32x4 hi = *(const i32x4*)&Bs[(nr + i * 16) * 128 + c1 * 16];
            bfr[i][0] = lo[0]; bfr[i][1] = lo[1]; bfr[i][2] = lo[2]; bfr[i][3] = lo[3];
            bfr[i][4] = hi[0]; bfr[i][5] = hi[1]; bfr[i][6] = hi[2]; bfr[i][7] = hi[3];
        }
#pragma unroll
        for (int mi = 0; mi < 4; ++mi)
#pragma unroll
            for (int ni = 0; ni < 4; ++ni)
                acc[mi][ni] = __builtin_amdgcn_mfma_scale_f32_16x16x128_f8f6f4(
                    af[mi], bfr[ni], acc[mi][ni], 0, 0, 0, 0x7F7F7F7F, 0, 0x79797979);
        __syncthreads();
    }

    bf16_t* out = parts + (size_t)ks * 4718592;
    int mbase = m0 + (wave >> 1) * 64 + (lane >> 4) * 4;
    int nbase = n0 + (wave & 1) * 64 + (lane & 15);
#pragma unroll
    for (int mi = 0; mi < 4; ++mi)
#pragma unroll
        for (int ni = 0; ni < 4; ++ni)
#pragma unroll
            for (int j = 0; j < 4; ++j)
                out[(size_t)(mbase + mi * 16 + j) * 256 + nbase + ni * 16] = (bf16_t)acc[mi][ni][j];
}

// ---------------- squash -> u bf16 [b][flat], flat = oc*36+pos ----------------
__global__ __launch_bounds__(256) void k_squash(const bf16_t* __restrict__ parts,
                                                const float* __restrict__ pcb,
                                                bf16_t* __restrict__ ub) {
    __shared__ float s[36 * 257];
    int b = blockIdx.x, tid = threadIdx.x;
    for (int i = tid; i < 9216; i += 256) {
        float a = pcb[i & 255];
#pragma unroll
        for (int p = 0; p < 2; ++p) a += (float)parts[(size_t)p * 4718592 + (size_t)b * 9216 + i];
        s[(i >> 8) * 257 + (i & 255)] = a;
    }
    __syncthreads();
    for (int r = tid; r < 1152; r += 256) {
        int flat0 = r * 8;
        float val[8], sn = 0.f;
#pragma unroll
        for (int e = 0; e < 8; ++e) {
            int f = flat0 + e;
            float x = s[(f % 36) * 257 + f / 36];
            val[e] = x;
            sn += x * x;
        }
        float scale = sn / ((1.f + sn) * sqrtf(sn));
        bf16x8 vv;
#pragma unroll
        for (int e = 0; e < 8; ++e) vv[e] = (bf16_t)(val[e] * scale);
        *(bf16x8*)&ub[(size_t)b * 9216 + flat0] = vv;
    }
}

// ---------------- u bf16 [512][9216] -> uT bf16 [9216][512] ----------------
__global__ __launch_bounds__(256) void k_uT(const bf16_t* __restrict__ ub, bf16_t* __restrict__ uT) {
    __shared__ bf16_t t[64 * 66];
    int kt = blockIdx.x % 144, bt = blockIdx.x / 144;
    int k0 = kt * 64, b0 = bt * 64;
    int tid = threadIdx.x;
    int c8 = tid & 7;
#pragma unroll
    for (int p = 0; p < 2; ++p) {
        int r = p * 32 + (tid >> 3);  // b-local
        bf16x8 vv = *(const bf16x8*)&ub[(size_t)(b0 + r) * 9216 + k0 + c8 * 8];
        uint32_t u4[4];
        *(bf16x8*)u4 = vv;
#pragma unroll
        for (int j2 = 0; j2 < 4; ++j2)
            *(uint32_t*)&t[r * 66 + c8 * 8 + j2 * 2] = u4[j2];
    }
    __syncthreads();
#pragma unroll
    for (int p = 0; p < 2; ++p) {
        int kp = p * 32 + (tid >> 3);  // k-local
        bf16x8 vv;
#pragma unroll
        for (int j = 0; j < 8; ++j) vv[j] = t[(c8 * 8 + j) * 66 + kp];
        *(bf16x8*)&uT[(size_t)(k0 + kp) * 512 + b0 + c8 * 8] = vv;
    }
}

// ---------------- cij = softmax_r(bij) per caps column (10 blocks) ----------------
__global__ void k_cij(const float* __restrict__ bij, float* __restrict__ cij) {
    __shared__ float red[256];
    int c = blockIdx.x, tid = threadIdx.x;
    float mx = -1e30f;
    for (int r = tid; r < 1152; r += 256) mx = fmaxf(mx, bij[r * 10 + c]);
    red[tid] = mx; __syncthreads();
    for (int s = 128; s > 0; s >>= 1) { if (tid < s) red[tid] = fmaxf(red[tid], red[tid + s]); __syncthreads(); }
    float MX = red[0]; __syncthreads();
    float sm = 0.f;
    for (int r = tid; r < 1152; r += 256) sm += expf(bij[r * 10 + c] - MX);
    red[tid] = sm; __syncthreads();
    for (int s = 128; s > 0; s >>= 1) { if (tid < s) red[tid] += red[tid + s]; __syncthreads(); }
    float inv = 1.f / red[0];
    for (int r = tid; r < 1152; r += 256) cij[r * 10 + c] = expf(bij[r * 10 + c] - MX) * inv;
}

// ---------------- fold: cw2T[co][k] = cij[r][c] * W[r][c][o][i] ----------------
__global__ void k_fold(const float* __restrict__ cij, const float* __restrict__ W,
                       bf16_t* __restrict__ cw2T) {
    int idx = blockIdx.x * 256 + threadIdx.x;  // 1474560, co-major
    int co = idx / 9216, k = idx % 9216;
    int r = k >> 3, i = k & 7;
    int c = co >> 4, o = co & 15;
    cw2T[idx] = (bf16_t)(cij[r * 10 + c] * W[((size_t)(r * 10 + c) * 16 + o) * 8 + i]);
}

// fold for iter0: bij=0 -> cij = 1/1152 uniform (no softmax needed)
__global__ void k_fold0(const float* __restrict__ W, bf16_t* __restrict__ cw2T) {
    int idx = blockIdx.x * 256 + threadIdx.x;  // 1474560
    int co = idx / 9216, k = idx % 9216;
    int r = k >> 3, i = k & 7;
    int c = co >> 4, o = co & 15;
    cw2T[idx] = (bf16_t)(W[((size_t)(r * 10 + c) * 16 + o) * 8 + i] * (1.0f / 1152.0f));
}

// ---------------- NT MFMA kernel: sp[ks][M][160] (bf16) = A[M][K] x B[160][K]^T ----------------
__global__ __launch_bounds__(256) void k_rgemm(const bf16_t* __restrict__ A,
                                               const bf16_t* __restrict__ B,
                                               bf16_t* __restrict__ Cp,
                                               int Kfull, int steps, int mtiles) {
    __shared__ __align__(16) bf16_t As[64 * 64];
    __shared__ __align__(16) bf16_t Bs[160 * 64];
    int bid = blockIdx.x;
    int mt = bid % mtiles, ks = bid / mtiles;
    int m0 = mt * 64;
    int k0 = ks * steps * 64;
    int tid = threadIdx.x, lane = tid & 63, wave = tid >> 6;
    int srow = tid >> 3;                       // 0..31
    int csrc = (tid & 7) ^ (srow & 7);
    const bf16_t* asrc[2];
    const bf16_t* bsrc[5];
#pragma unroll
    for (int p = 0; p < 2; ++p)
        asrc[p] = A + (size_t)(m0 + p * 32 + srow) * Kfull + k0 + csrc * 8;
#pragma unroll
    for (int p = 0; p < 5; ++p)
        bsrc[p] = B + (size_t)(p * 32 + srow) * Kfull + k0 + csrc * 8;

    f32x4 acc[2][5];
#pragma unroll
    for (int mi = 0; mi < 2; ++mi)
#pragma unroll
        for (int nj = 0; nj < 5; ++nj) acc[mi][nj] = (f32x4){0.f, 0.f, 0.f, 0.f};

    int mr = (wave >> 1) * 32 + (lane & 15);
    int nr = (wave & 1) * 80 + (lane & 15);
    int rx = lane & 7;

    for (int it = 0; it < steps; ++it) {
#pragma unroll
        for (int p = 0; p < 2; ++p) gload_lds16(asrc[p] + it * 64, As + p * 2048 + tid * 8);
#pragma unroll
        for (int p = 0; p < 5; ++p) gload_lds16(bsrc[p] + it * 64, Bs + p * 2048 + tid * 8);
        __syncthreads();
#pragma unroll
        for (int kk = 0; kk < 2; ++kk) {
            int ch = ((kk * 4 + (lane >> 4)) ^ rx) * 8;
            bf16x8 af[2], bfr[5];
#pragma unroll
            for (int i = 0; i < 2; ++i) af[i] = *(const bf16x8*)&As[(mr + i * 16) * 64 + ch];
#pragma unroll
            for (int j = 0; j < 5; ++j) bfr[j] = *(const bf16x8*)&Bs[(nr + j * 16) * 64 + ch];
#pragma unroll
            for (int mi = 0; mi < 2; ++mi)
#pragma unroll
                for (int nj = 0; nj < 5; ++nj)
                    acc[mi][nj] = __builtin_amdgcn_mfma_f32_16x16x32_bf16(af[mi], bfr[nj], acc[mi][nj], 0, 0, 0);
        }
        __syncthreads();
    }

    bf16_t* out = Cp + (size_t)ks * ((size_t)mtiles * 64 * 160);
    int mbase = m0 + (wave >> 1) * 32 + (lane >> 4) * 4;
    int nbase = (wave & 1) * 80 + (lane & 15);
#pragma unroll
    for (int mi = 0; mi < 2; ++mi)
#pragma unroll
        for (int nj = 0; nj < 5; ++nj)
#pragma unroll
            for (int j = 0; j < 4; ++j)
                out[(size_t)(mbase + mi * 16 + j) * 160 + nbase + nj * 16] = (bf16_t)acc[mi][nj][j];
}

// ---------------- v + vT from bf16 s partials ----------------
__global__ void k_vcomp(const bf16_t* __restrict__ sp, float* __restrict__ v,
                        bf16_t* __restrict__ vT) {
    int idx = blockIdx.x * 256 + threadIdx.x;  // 81920
    float s = 0.f;
#pragma unroll
    for (int p = 0; p < 36; ++p) s += (float)sp[(size_t)p * 81920 + idx];
    float val = s * fabsf(s) / (1.f + s * s);
    v[idx] = val;
    int b = idx / 160, co = idx % 160;
    vT[(size_t)co * 512 + b] = (bf16_t)val;
}

// ---------------- G-gemm + amean fused ----------------
__global__ __launch_bounds__(256) void k_ggemm2(const bf16_t* __restrict__ uT,
                                                const bf16_t* __restrict__ vT,
                                                const float* __restrict__ W,
                                                float* __restrict__ bij) {
    __shared__ __align__(16) bf16_t As[64 * 64];
    __shared__ __align__(16) bf16_t Bs[160 * 64];
    __shared__ float Gl[64 * 161];
    int mt = blockIdx.x;
    int m0 = mt * 64;
    int tid = threadIdx.x, lane = tid & 63, wave = tid >> 6;
    int srow = tid >> 3;
    int csrc = (tid & 7) ^ (srow & 7);
    const bf16_t* asrc[2];
    const bf16_t* bsrc[5];
#pragma unroll
    for (int p = 0; p < 2; ++p)
        asrc[p] = uT + (size_t)(m0 + p * 32 + srow) * 512 + csrc * 8;
#pragma unroll
    for (int p = 0; p < 5; ++p)
        bsrc[p] = vT + (size_t)(p * 32 + srow) * 512 + csrc * 8;

    f32x4 acc[2][5];
#pragma unroll
    for (int mi = 0; mi < 2; ++mi)
#pragma unroll
        for (int nj = 0; nj < 5; ++nj) acc[mi][nj] = (f32x4){0.f, 0.f, 0.f, 0.f};

    int mr = (wave >> 1) * 32 + (lane & 15);
    int nr = (wave & 1) * 80 + (lane & 15);
    int rx = lane & 7;

    for (int it = 0; it < 8; ++it) {
#pragma unroll
        for (int p = 0; p < 2; ++p) gload_lds16(asrc[p] + it * 64, As + p * 2048 + tid * 8);
#pragma unroll
        for (int p = 0; p < 5; ++p) gload_lds16(bsrc[p] + it * 64, Bs + p * 2048 + tid * 8);
        __syncthreads();
#pragma unroll
        for (int kk = 0; kk < 2; ++kk) {
            int ch = ((kk * 4 + (lane >> 4)) ^ rx) * 8;
            bf16x8 af[2], bfr[5];
#pragma unroll
            for (int i = 0; i < 2; ++i) af[i] = *(const bf16x8*)&As[(mr + i * 16) * 64 + ch];
#pragma unroll
            for (int j = 0; j < 5; ++j) bfr[j] = *(const bf16x8*)&Bs[(nr + j * 16) * 64 + ch];
#pragma unroll
            for (int mi = 0; mi < 2; ++mi)
#pragma unroll
                for (int nj = 0; nj < 5; ++nj)
                    acc[mi][nj] = __builtin_amdgcn_mfma_f32_16x16x32_bf16(af[mi], bfr[nj], acc[mi][nj], 0, 0, 0);
        }
        __syncthreads();
    }

    int mbl = (wave >> 1) * 32 + (lane >> 4) * 4;
    int nbase = (wave & 1) * 80 + (lane & 15);
#pragma unroll
    for (int mi = 0; mi < 2; ++mi)
#pragma unroll
        for (int nj = 0; nj < 5; ++nj)
#pragma unroll
            for (int j = 0; j < 4; ++j)
                Gl[(mbl + mi * 16 + j) * 161 + nbase + nj * 16] = acc[mi][nj][j] * (1.0f / 512.0f);
    __syncthreads();
    if (tid < 80) {
        int rl = tid / 10, c = tid % 10;
        int r = mt * 8 + rl;
        const float* wbase = W + (size_t)(r * 10 + c) * 128;
        float s = 0.f;
#pragma unroll
        for (int o = 0; o < 16; ++o)
#pragma unroll
            for (int i = 0; i < 8; ++i)
                s += wbase[o * 8 + i] * Gl[(rl * 8 + i) * 161 + c * 16 + o];
        bij[r * 10 + c] += s;
    }
}

// ---------------- encoder (enc1+enc2 fused) ----------------
__global__ __launch_bounds__(256) void k_enc(const float* __restrict__ v,
                                             const float* __restrict__ w1t,
                                             const float* __restrict__ b1,
                                             const float* __restrict__ w2,
                                             const float* __restrict__ b2,
                                             float* __restrict__ out) {
    __shared__ float fl[160];
    __shared__ float h[512];
    int b = blockIdx.x, tid = threadIdx.x;
    if (tid < 160) fl[tid] = v[b * 160 + tid];
    __syncthreads();
    for (int j = tid; j < 512; j += 256) {
        float s = b1[j];
#pragma unroll 8
        for (int k = 0; k < 160; ++k) s += fl[k] * w1t[k * 512 + j];
        h[j] = fmaxf(s, 0.f);
    }
    __syncthreads();
    int wave = tid >> 6, lane = tid & 63;
    for (int j = wave; j < 9; j += 4) {
        float p = 0.f;
#pragma unroll
        for (int l = lane; l < 512; l += 64) p += h[l] * w2[j * 512 + l];
#pragma unroll
        for (int off = 32; off > 0; off >>= 1) p += __shfl_down(p, off, 64);
        if (lane == 0) out[b * 9 + j] = 1.f / (1.f + expf(-(p + b2[j])));
    }
}

// ---------------- launch ----------------
extern "C" void kernel_launch(void* const* d_in, const int* in_sizes, int n_in,
                              void* d_out, int out_size, void* d_ws, size_t ws_size,
                              hipStream_t stream) {
    const float* data   = (const float*)d_in[0];
    const float* conv_w = (const float*)d_in[1];
    const float* conv_b = (const float*)d_in[2];
    const float* pc_w   = (const float*)d_in[3];
    const float* pc_b   = (const float*)d_in[4];
    const float* W      = (const float*)d_in[5];
    const float* enc_w1 = (const float*)d_in[6];
    const float* enc_b1 = (const float*)d_in[7];
    const float* enc_w2 = (const float*)d_in[8];
    const float* enc_b2 = (const float*)d_in[9];

    char* ws = (char*)d_ws;
    uint8_t* xt8   = (uint8_t*)(ws + 0);           //  52,428,800
    uint8_t* w2t8  = (uint8_t*)(ws + 52428800);    //   5,308,416 ->  57,737,216
    bf16_t*  parts = (bf16_t*)(ws + 57737216);     //  18,874,368 (2 x 9,437,184 B) -> 76,611,584
    bf16_t*  uT    = (bf16_t*)(ws + 76611584);     //   9,437,184 ->  86,048,768
    bf16_t*  cw2T  = (bf16_t*)(ws + 86048768);     //   2,949,120 ->  88,997,888
    bf16_t*  sp    = (bf16_t*)(ws + 88997888);     //   5,898,240 ->  94,896,128
    bf16_t*  ub    = (bf16_t*)(ws + 94896128);     //   9,437,184 -> 104,333,312
    float*   v     = (float*)(ws + 104333312);     //     327,680 -> 104,660,992
    bf16_t*  vT    = (bf16_t*)(ws + 104660992);    //     163,840 -> 104,824,832
    float*   w1t   = (float*)(ws + 104824832);     //     327,680 -> 105,152,512
    float*   bij   = (float*)(ws + 105152512);     //      46,080 -> 105,198,592
    float*   cij   = (float*)(ws + 105198592);     //      46,080 -> 105,244,672
    bf16_t*  Bc1   = (bf16_t*)(ws + 105244672);    //      53,248 -> 105,297,920 total
    float*   outp  = (float*)d_out;

    hipLaunchKernelGGL(k_prep, dim3(469), dim3(256), 0, stream, enc_w1, conv_w, w1t, Bc1, bij);
    hipLaunchKernelGGL(k_w2t, dim3(256), dim3(256), 0, stream, pc_w, w2t8);
    hipLaunchKernelGGL(k_c1gemm, dim3(800), dim3(512), 0, stream, data, Bc1, conv_b, xt8);
    hipLaunchKernelGGL(k_pcgemm, dim3(576), dim3(256), 0, stream, xt8, w2t8, parts);
    hipLaunchKernelGGL(k_squash, dim3(512), dim3(256), 0, stream, parts, pc_b, ub);
    hipLaunchKernelGGL(k_uT, dim3(1152), dim3(256), 0, stream, ub, uT);
    for (int it = 0; it < 3; ++it) {
        if (it == 0) {
            hipLaunchKernelGGL(k_fold0, dim3(5760), dim3(256), 0, stream, W, cw2T);
        } else {
            hipLaunchKernelGGL(k_cij, dim3(10), dim3(256), 0, stream, bij, cij);
            hipLaunchKernelGGL(k_fold, dim3(5760), dim3(256), 0, stream, cij, W, cw2T);
        }
        hipLaunchKernelGGL(k_rgemm, dim3(288), dim3(256), 0, stream, ub, cw2T, sp, 9216, 4, 8);
        hipLaunchKernelGGL(k_vcomp, dim3(320), dim3(256), 0, stream, sp, v, vT);
        if (it < 2) {
            hipLaunchKernelGGL(k_ggemm2, dim3(144), dim3(256), 0, stream, uT, vT, W, bij);
        }
    }
    hipLaunchKernelGGL(k_enc, dim3(512), dim3(256), 0, stream, v, w1t, enc_b1, enc_w2, enc_b2, outp);
}